// Round 7
// baseline (244.745 us; speedup 1.0000x reference)
//
#include <hip/hip_runtime.h>

typedef unsigned short u16;
typedef unsigned int u32;
typedef __attribute__((ext_vector_type(8))) short bf16x8;
typedef __attribute__((ext_vector_type(4))) short bf16x4;
typedef __attribute__((ext_vector_type(4))) float f32x4;

#define CSC 0.1803368801111244f  // 0.125 * log2(e), folded into K at projection

__device__ __forceinline__ u16 f2b(float f) {
  union { float f; u32 u; } c; c.f = f;
  return (u16)((c.u + 0x8000u) >> 16);
}

__device__ __forceinline__ uint2 pk4(f32x4 p) {
  union { float f; u32 u; } c0, c1, c2, c3;
  c0.f = p[0]; c1.f = p[1]; c2.f = p[2]; c3.f = p[3];
  u32 a = c0.u + 0x8000u, b = c1.u + 0x8000u;
  u32 c = c2.u + 0x8000u, d = c3.u + 0x8000u;
  uint2 r;
  r.x = __builtin_amdgcn_perm(b, a, 0x07060302u);
  r.y = __builtin_amdgcn_perm(d, c, 0x07060302u);
  return r;
}

__device__ __forceinline__ bf16x4 pk4v(f32x4 p) {
  union { uint2 u; bf16x4 v; } c;
  c.u = pk4(p);
  return c.v;
}

__device__ __forceinline__ void async16(const void* g, void* s) {
  __builtin_amdgcn_global_load_lds(
      (const __attribute__((address_space(1))) u32*)g,
      (__attribute__((address_space(3))) u32*)s, 16, 0, 0);
}

// ---------------- fused prep ----------------
__global__ void prep(const float* __restrict__ x, const float* __restrict__ ctx,
                     const int* __restrict__ mask,
                     const float* __restrict__ Wq, const float* __restrict__ Wk,
                     const float* __restrict__ Wv, const float* __restrict__ Wo,
                     u16* __restrict__ Xb, u16* __restrict__ Cb,
                     float* __restrict__ mvalid, float* __restrict__ cnt,
                     u16* __restrict__ Wtq, u16* __restrict__ Wtkv, u16* __restrict__ Wto) {
  __shared__ u16 Tl[64 * 65];
  __shared__ int cred[4];
  const int bid = blockIdx.x, tid = threadIdx.x;
  if (bid < 10240) {
    const float* src; u16* dst; int i;
    if (bid < 4096) { i = (bid * 256 + tid) * 4; src = x; dst = Xb; }
    else { i = ((bid - 4096) * 256 + tid) * 4; src = ctx; dst = Cb; }
    float4 f = *(const float4*)&src[i];
    ushort4 o;
    o.x = f2b(f.x); o.y = f2b(f.y); o.z = f2b(f.z); o.w = f2b(f.w);
    *(ushort4*)&dst[i] = o;
  } else if (bid < 10560) {
    int t = bid - 10240;
    const float* W; u16* Wt; int Kd, tt;
    if (t < 64)       { W = Wq; Wt = Wtq;  Kd = 512; tt = t; }
    else if (t < 160) { W = Wk; Wt = Wtkv; Kd = 768; tt = t - 64; }
    else if (t < 256) { W = Wv; Wt = Wtkv + (size_t)512 * 768; Kd = 768; tt = t - 160; }
    else              { W = Wo; Wt = Wto;  Kd = 512; tt = t - 256; }
    const int k0 = (tt >> 3) * 64, n0 = (tt & 7) * 64;
    {
      const int r = tid >> 2, cg = (tid & 3) * 16;
#pragma unroll
      for (int i = 0; i < 4; i++) {
        float4 f = *(const float4*)&W[(size_t)(k0 + r) * 512 + n0 + cg + i * 4];
        Tl[r * 65 + cg + i * 4 + 0] = f2b(f.x);
        Tl[r * 65 + cg + i * 4 + 1] = f2b(f.y);
        Tl[r * 65 + cg + i * 4 + 2] = f2b(f.z);
        Tl[r * 65 + cg + i * 4 + 3] = f2b(f.w);
      }
    }
    __syncthreads();
    {
      const int n = tid >> 2, kg = (tid & 3) * 16;
      u16 buf[16];
#pragma unroll
      for (int i = 0; i < 16; i++) buf[i] = Tl[(kg + i) * 65 + n];
      u16* dst = &Wt[(size_t)(n0 + n) * Kd + k0 + kg];
      *(uint4*)dst = *(const uint4*)&buf[0];
      *(uint4*)(dst + 8) = *(const uint4*)&buf[8];
    }
  } else {
    const int b = bid - 10560;
    const int base = b * 4096;
    const int w = tid >> 6, lane = tid & 63;
    int zc = 0;
#pragma unroll
    for (int j = 0; j < 16; j++) {
      int idx = tid + j * 256;
      int mv = mask[base + idx];
      mvalid[base + idx] = mv ? 1.f : 0.f;
      zc += (mv == 0);
    }
#pragma unroll
    for (int d = 1; d < 64; d <<= 1) zc += __shfl_xor(zc, d);
    if (lane == 0) cred[w] = zc;
    __syncthreads();
    if (tid == 0) cnt[b] = (float)(cred[0] + cred[1] + cred[2] + cred[3]);
  }
}

// ---------------- fused QKV projection GEMM, 64x128 tiles ----------------
__global__ __launch_bounds__(256, 6)
void gemm_qkv(const u16* __restrict__ Xb, const u16* __restrict__ Cb,
              const u16* __restrict__ Wtq, const u16* __restrict__ Wtkv,
              const float* __restrict__ mvalid,
              u16* __restrict__ Qb, u16* __restrict__ Kb, u16* __restrict__ Vt) {
  __shared__ u16 As[64 * 64];
  __shared__ u16 Bs[128 * 64];
  const int tid = threadIdx.x;
  const int w = tid >> 6, lane = tid & 63, quad = lane >> 4, l16 = lane & 15;
  const int wr = w >> 1, wc = w & 1;
  const int y = blockIdx.y;
  const bool isQ = (y < 4);
  const u16* A  = isQ ? Xb : Cb;
  const u16* Bt = isQ ? Wtq : Wtkv;
  const int K   = isQ ? 512 : 768;
  const int n0  = isQ ? y * 128 : (y - 4) * 128;
  const size_t m0 = (size_t)blockIdx.x * 64;
  const u16* Ab = A + m0 * K;
  const u16* Bb = Bt + (size_t)n0 * K;

  const int cswz = (((lane & 7) ^ ((lane >> 3) & 7)) << 3);
  const int sw0 = ((quad ^ (l16 & 7)) << 3);
  const int sw1 = sw0 ^ 32;
  const int r8 = lane >> 3;

  f32x4 acc[2][4];
#pragma unroll
  for (int i = 0; i < 2; i++)
#pragma unroll
    for (int j = 0; j < 4; j++) acc[i][j] = (f32x4){0.f, 0.f, 0.f, 0.f};

  for (int k0 = 0; k0 < K; k0 += 64) {
    async16(Ab + (size_t)(w * 16 + r8) * K + k0 + cswz, &As[(w * 16) * 64]);
    async16(Ab + (size_t)(w * 16 + 8 + r8) * K + k0 + cswz, &As[(w * 16 + 8) * 64]);
#pragma unroll
    for (int t = 0; t < 4; t++)
      async16(Bb + (size_t)(w * 32 + t * 8 + r8) * K + k0 + cswz, &Bs[(w * 32 + t * 8) * 64]);
    __syncthreads();
#pragma unroll
    for (int ks = 0; ks < 2; ks++) {
      const int so = ks ? sw1 : sw0;
      bf16x8 af[2], bfr[4];
#pragma unroll
      for (int i = 0; i < 2; i++)
        af[i] = *(const bf16x8*)&As[(wr * 32 + i * 16 + l16) * 64 + so];
#pragma unroll
      for (int j = 0; j < 4; j++)
        bfr[j] = *(const bf16x8*)&Bs[(wc * 64 + j * 16 + l16) * 64 + so];
#pragma unroll
      for (int i = 0; i < 2; i++)
#pragma unroll
        for (int j = 0; j < 4; j++)
          acc[i][j] = __builtin_amdgcn_mfma_f32_16x16x32_bf16(af[i], bfr[j], acc[i][j], 0, 0, 0);
    }
    __syncthreads();
  }

  if (isQ) {
#pragma unroll
    for (int i = 0; i < 2; i++)
#pragma unroll
      for (int j = 0; j < 4; j++)
#pragma unroll
        for (int r = 0; r < 4; r++) {
          size_t row = m0 + wr * 32 + i * 16 + quad * 4 + r;
          Qb[row * 512 + n0 + wc * 64 + j * 16 + l16] = f2b(acc[i][j][r]);
        }
  } else if (n0 < 512) {
#pragma unroll
    for (int i = 0; i < 2; i++) {
      size_t row0 = m0 + wr * 32 + i * 16 + quad * 4;
      f32x4 vm = *(const f32x4*)&mvalid[row0];
#pragma unroll
      for (int j = 0; j < 4; j++)
#pragma unroll
        for (int r = 0; r < 4; r++)
          Kb[(row0 + r) * 512 + n0 + wc * 64 + j * 16 + l16] = f2b(acc[i][j][r] * (vm[r] * CSC));
    }
  } else {
#pragma unroll
    for (int i = 0; i < 2; i++) {
      size_t row0 = m0 + wr * 32 + i * 16 + quad * 4;
      f32x4 vm = *(const f32x4*)&mvalid[row0];
#pragma unroll
      for (int j = 0; j < 4; j++) {
        int d = n0 - 512 + wc * 64 + j * 16 + l16;
        f32x4 v;
#pragma unroll
        for (int r = 0; r < 4; r++) v[r] = acc[i][j][r] * vm[r];
        *(uint2*)&Vt[(size_t)d * 8192 + row0] = pk4(v);
      }
    }
  }
}

// ---------------- O projection: 64x64 tiles ----------------
__global__ __launch_bounds__(256, 4)
void gemm_o(const u16* __restrict__ A, const u16* __restrict__ Bt,
            const float* __restrict__ bias, float* __restrict__ Cf) {
  __shared__ u16 As[64 * 64];
  __shared__ u16 Bs[64 * 64];
  const int tid = threadIdx.x;
  const int w = tid >> 6, lane = tid & 63, quad = lane >> 4, l16 = lane & 15;
  const size_t m0 = (size_t)blockIdx.x * 64;
  const int n0 = blockIdx.y * 64;
  const u16* Ab = A + m0 * 512;
  const u16* Bb = Bt + (size_t)n0 * 512;

  const int cswz = (((lane & 7) ^ ((lane >> 3) & 7)) << 3);
  const int sw0 = ((quad ^ (l16 & 7)) << 3);
  const int sw1 = sw0 ^ 32;
  const int r8 = lane >> 3;

  f32x4 acc[4];
#pragma unroll
  for (int j = 0; j < 4; j++) acc[j] = (f32x4){0.f, 0.f, 0.f, 0.f};

  for (int k0 = 0; k0 < 512; k0 += 64) {
    async16(Ab + (size_t)(w * 16 + r8) * 512 + k0 + cswz, &As[(w * 16) * 64]);
    async16(Ab + (size_t)(w * 16 + 8 + r8) * 512 + k0 + cswz, &As[(w * 16 + 8) * 64]);
    async16(Bb + (size_t)(w * 16 + r8) * 512 + k0 + cswz, &Bs[(w * 16) * 64]);
    async16(Bb + (size_t)(w * 16 + 8 + r8) * 512 + k0 + cswz, &Bs[(w * 16 + 8) * 64]);
    __syncthreads();
#pragma unroll
    for (int ks = 0; ks < 2; ks++) {
      const int so = ks ? sw1 : sw0;
      bf16x8 af = *(const bf16x8*)&As[(w * 16 + l16) * 64 + so];
#pragma unroll
      for (int j = 0; j < 4; j++) {
        bf16x8 bfr = *(const bf16x8*)&Bs[(j * 16 + l16) * 64 + so];
        acc[j] = __builtin_amdgcn_mfma_f32_16x16x32_bf16(af, bfr, acc[j], 0, 0, 0);
      }
    }
    __syncthreads();
  }

#pragma unroll
  for (int j = 0; j < 4; j++)
#pragma unroll
    for (int r = 0; r < 4; r++) {
      size_t row = m0 + w * 16 + quad * 4 + r;
      int col = n0 + j * 16 + l16;
      Cf[row * 512 + col] = acc[j][r] + bias[col];
    }
}

// ---------------- flash attention: round-4 structure + 2-way m-split ----------------
// grid 1024: l&15 = hb (h=hb>>1, b=hb&1), (l>>4)&1 = m-half, l>>5 = qb (128-q tile).
// Wave owns 32 q rows x all 2048 m of its half. Fixed-max softmax => partials add.
__global__ __launch_bounds__(256, 4)
void attn_kernel(const u16* __restrict__ Q, const u16* __restrict__ Kg,
                 const u16* __restrict__ Vt,
                 float* __restrict__ Opart, float* __restrict__ Lpart) {
  __shared__ u16 Ks[2][64 * 64];
  __shared__ u16 Vs[2][64 * 64];

  const int tid = threadIdx.x;
  const int w = tid >> 6, lane = tid & 63, quad = lane >> 4, l16 = lane & 15;
  const int l = blockIdx.x;
  const int hb = l & 15, half = (l >> 4) & 1, qb = l >> 5;
  const int h = hb >> 1, b = hb & 1;
  const size_t qrow0 = (size_t)b * 4096 + (size_t)qb * 128;
  const size_t crow0 = (size_t)b * 4096 + (size_t)half * 2048;
  const int hcol = h * 64;

  const int cswz = (((lane & 7) ^ ((lane >> 3) & 7)) << 3);
  const int sw0 = ((quad ^ (l16 & 7)) << 3);
  const int sw1 = sw0 ^ 32;
  const int r8 = lane >> 3;

  bf16x8 qf[2][2];
#pragma unroll
  for (int qt = 0; qt < 2; qt++)
#pragma unroll
    for (int ks = 0; ks < 2; ks++)
      qf[qt][ks] = *(const bf16x8*)&Q[(qrow0 + w * 32 + qt * 16 + l16) * 512 + hcol + ks * 32 + quad * 8];

  async16(Kg + (crow0 + w * 16 + r8) * 512 + hcol + cswz, &Ks[0][(w * 16) * 64]);
  async16(Kg + (crow0 + w * 16 + 8 + r8) * 512 + hcol + cswz, &Ks[0][(w * 16 + 8) * 64]);
  async16(Vt + (size_t)(hcol + w * 16 + r8) * 8192 + crow0 + cswz, &Vs[0][(w * 16) * 64]);
  async16(Vt + (size_t)(hcol + w * 16 + 8 + r8) * 8192 + crow0 + cswz, &Vs[0][(w * 16 + 8) * 64]);
  __syncthreads();

  f32x4 Oacc[2][4];
#pragma unroll
  for (int qt = 0; qt < 2; qt++)
#pragma unroll
    for (int dt = 0; dt < 4; dt++) Oacc[qt][dt] = (f32x4){0.f, 0.f, 0.f, 0.f};
  float lsum[2] = {0.f, 0.f};

  for (int mt = 0; mt < 32; mt++) {
    const int cur = mt & 1;

    if (mt < 31) {
      const size_t mn = crow0 + (size_t)(mt + 1) * 64;
      async16(Kg + (mn + w * 16 + r8) * 512 + hcol + cswz, &Ks[cur ^ 1][(w * 16) * 64]);
      async16(Kg + (mn + w * 16 + 8 + r8) * 512 + hcol + cswz, &Ks[cur ^ 1][(w * 16 + 8) * 64]);
      async16(Vt + (size_t)(hcol + w * 16 + r8) * 8192 + mn + cswz, &Vs[cur ^ 1][(w * 16) * 64]);
      async16(Vt + (size_t)(hcol + w * 16 + 8 + r8) * 8192 + mn + cswz, &Vs[cur ^ 1][(w * 16 + 8) * 64]);
    }

    f32x4 sacc[2][4];
#pragma unroll
    for (int qt = 0; qt < 2; qt++)
#pragma unroll
      for (int mtt = 0; mtt < 4; mtt++) sacc[qt][mtt] = (f32x4){0.f, 0.f, 0.f, 0.f};
#pragma unroll
    for (int ks = 0; ks < 2; ks++) {
      const int so = ks ? sw1 : sw0;
      bf16x8 kb[4];
#pragma unroll
      for (int mtt = 0; mtt < 4; mtt++)
        kb[mtt] = *(const bf16x8*)&Ks[cur][(mtt * 16 + l16) * 64 + so];
#pragma unroll
      for (int qt = 0; qt < 2; qt++)
#pragma unroll
        for (int mtt = 0; mtt < 4; mtt++)
          sacc[qt][mtt] = __builtin_amdgcn_mfma_f32_16x16x32_bf16(kb[mtt], qf[qt][ks], sacc[qt][mtt], 0, 0, 0);
    }

    bf16x4 pf[2][4];
#pragma unroll
    for (int qt = 0; qt < 2; qt++) {
      float rs = 0.f;
#pragma unroll
      for (int mtt = 0; mtt < 4; mtt++) {
        f32x4 p;
#pragma unroll
        for (int r = 0; r < 4; r++) {
          p[r] = __builtin_amdgcn_exp2f(sacc[qt][mtt][r]);
          rs += p[r];
        }
        pf[qt][mtt] = pk4v(p);
      }
      lsum[qt] += rs;
    }

#pragma unroll
    for (int mtt = 0; mtt < 4; mtt++) {
      bf16x4 va[4];
#pragma unroll
      for (int dt = 0; dt < 4; dt++)
        va[dt] = *(const bf16x4*)&Vs[cur][(dt * 16 + l16) * 64 +
                      (((mtt * 2 + (quad >> 1)) ^ (l16 & 7)) << 3) + ((quad & 1) << 2)];
#pragma unroll
      for (int qt = 0; qt < 2; qt++)
#pragma unroll
        for (int dt = 0; dt < 4; dt++)
          Oacc[qt][dt] = __builtin_amdgcn_mfma_f32_16x16x16bf16_1k(va[dt], pf[qt][mtt], Oacc[qt][dt], 0, 0, 0);
    }
    __syncthreads();
  }

#pragma unroll
  for (int qt = 0; qt < 2; qt++) {
    lsum[qt] += __shfl_xor(lsum[qt], 16);
    lsum[qt] += __shfl_xor(lsum[qt], 32);
    if (quad == 0)
      Lpart[(size_t)half * 65536 + ((b * 8 + h) << 12) + qb * 128 + w * 32 + qt * 16 + l16] = lsum[qt];
  }

  float* Obuf = Opart + (size_t)half * 8192 * 512;
#pragma unroll
  for (int qt = 0; qt < 2; qt++)
#pragma unroll
    for (int dt = 0; dt < 4; dt++)
      *(f32x4*)&Obuf[(qrow0 + w * 32 + qt * 16 + l16) * 512 + hcol + dt * 16 + quad * 4] = Oacc[qt][dt];
}

// ---------------- combine: AO = bf16((O0+O1) / (l0+l1-cnt)) ----------------
__global__ void combine(const float* __restrict__ Opart, const float* __restrict__ Lpart,
                        const float* __restrict__ cnt, u16* __restrict__ AOb) {
  const int idx = blockIdx.x * 256 + threadIdx.x;   // 1,048,576 threads x 4 f32
  const int row = idx >> 7, c4 = (idx & 127) << 2;
  const int b = row >> 12, q = row & 4095, h = c4 >> 6;
  const int li = ((b * 8 + h) << 12) + q;
  const float inv = 1.0f / (Lpart[li] + Lpart[65536 + li] - cnt[b]);
  const size_t off = (size_t)row * 512 + c4;
  f32x4 o0 = *(const f32x4*)&Opart[off];
  f32x4 o1 = *(const f32x4*)&Opart[(size_t)8192 * 512 + off];
  f32x4 o;
#pragma unroll
  for (int r = 0; r < 4; r++) o[r] = (o0[r] + o1[r]) * inv;
  *(uint2*)&AOb[off] = pk4(o);
}

// ---------------- host ----------------

extern "C" void kernel_launch(void* const* d_in, const int* in_sizes, int n_in,
                              void* d_out, int out_size, void* d_ws, size_t ws_size,
                              hipStream_t stream) {
  const float* x   = (const float*)d_in[0];
  const float* ctx = (const float*)d_in[1];
  const int*  mask = (const int*)d_in[2];
  const float* Wq  = (const float*)d_in[3];
  const float* Wk  = (const float*)d_in[4];
  const float* Wv  = (const float*)d_in[5];
  const float* Wo  = (const float*)d_in[6];
  const float* bo  = (const float*)d_in[7];
  float* out = (float*)d_out;

  char* p = (char*)d_ws;
  u16* Xb   = (u16*)p; p += (size_t)8192 * 512 * 2;
  u16* Cb   = (u16*)p; p += (size_t)8192 * 768 * 2;
  u16* Wtq  = (u16*)p; p += (size_t)512 * 512 * 2;
  u16* Wtkv = (u16*)p; p += (size_t)1024 * 768 * 2;
  u16* Wto  = (u16*)p; p += (size_t)512 * 512 * 2;
  u16* Qb   = (u16*)p; p += (size_t)8192 * 512 * 2;
  u16* Kb   = (u16*)p; p += (size_t)8192 * 512 * 2;
  u16* Vtg  = (u16*)p; p += (size_t)512 * 8192 * 2;
  u16* AOb  = (u16*)p; p += (size_t)8192 * 512 * 2;
  float* mvalid = (float*)p; p += (size_t)8192 * 4;
  float* cnt    = (float*)p; p += 256;
  float* Opart  = (float*)p; p += (size_t)2 * 8192 * 512 * 4;  // 33.6 MB, both halves
  float* Lpart  = (float*)p; p += (size_t)2 * 65536 * 4;       // 0.5 MB

  prep<<<10562, 256, 0, stream>>>(x, ctx, mask, Wq, Wk, Wv, Wo,
                                  Xb, Cb, mvalid, cnt, Wtq, Wtkv, Wto);
  gemm_qkv<<<dim3(128, 12), 256, 0, stream>>>(Xb, Cb, Wtq, Wtkv, mvalid, Qb, Kb, Vtg);
  attn_kernel<<<1024, 256, 0, stream>>>(Qb, Kb, Vtg, Opart, Lpart);
  combine<<<4096, 256, 0, stream>>>(Opart, Lpart, cnt, AOb);
  gemm_o<<<dim3(128, 8), 256, 0, stream>>>(AOb, Wto, bo, out);
}